// Round 2
// baseline (588.729 us; speedup 1.0000x reference)
//
#include <hip/hip_runtime.h>
#include <hip/hip_bf16.h>

typedef __bf16 bf16x8 __attribute__((ext_vector_type(8)));
typedef float  f32x4  __attribute__((ext_vector_type(4)));

#define GRU_H 128

__device__ inline bf16x8 load_frag_f32(const float* p) {
    // 8 consecutive floats -> bf16x8 fragment
    float4 a = *reinterpret_cast<const float4*>(p);
    float4 b = *reinterpret_cast<const float4*>(p + 4);
    bf16x8 r;
    r[0] = (__bf16)a.x; r[1] = (__bf16)a.y; r[2] = (__bf16)a.z; r[3] = (__bf16)a.w;
    r[4] = (__bf16)b.x; r[5] = (__bf16)b.y; r[6] = (__bf16)b.z; r[7] = (__bf16)b.w;
    return r;
}

__device__ inline float sigmoidf_(float x) { return 1.f / (1.f + __expf(-x)); }
__device__ inline float tanhf_(float x)    { return 1.f - 2.f / (__expf(2.f * x) + 1.f); }

// 512 threads = 8 waves. Wave w owns output-column tile w (16 cols of H=128).
// Each wave holds its 6 gate-weight slices (r,z,n for W_ih and W_hh) as bf16
// MFMA B-fragments in registers, loaded once. Block grid-strides over 16-row
// message chunks; per chunk: 24x mfma_f32_16x16x32_bf16, gate epilogue,
// scatter-store to out[node_ids[row]].
__global__ __launch_bounds__(512, 2) void gru_update_kernel(
    const int*   __restrict__ node_ids,
    const float* __restrict__ messages,
    const float* __restrict__ memory,
    const float* __restrict__ W_ih,
    const float* __restrict__ W_hh,
    const float* __restrict__ b_ih,
    const float* __restrict__ b_hh,
    float*       __restrict__ out,
    int B)
{
    const int wave = threadIdx.x >> 6;   // 0..7 -> column tile
    const int lane = threadIdx.x & 63;
    const int l15  = lane & 15;
    const int lg   = lane >> 4;          // 0..3
    const int col  = wave * 16 + l15;    // output column in [0,128)

    // B-fragments: B[k][n] = W[gate_off + n][k]; lane supplies n = l15,
    // k = ks*32 + lg*8 + i (i=0..7, contiguous).
    bf16x8 bfrag[6][4];
    #pragma unroll
    for (int g = 0; g < 3; ++g) {
        #pragma unroll
        for (int ks = 0; ks < 4; ++ks) {
            const int off = (g * GRU_H + col) * GRU_H + ks * 32 + lg * 8;
            bfrag[g][ks]     = load_frag_f32(W_ih + off);
            bfrag[g + 3][ks] = load_frag_f32(W_hh + off);
        }
    }
    const float bi_r = b_ih[col], bi_z = b_ih[GRU_H + col], bi_n = b_ih[2 * GRU_H + col];
    const float bh_r = b_hh[col], bh_z = b_hh[GRU_H + col], bh_n = b_hh[2 * GRU_H + col];

    const int nchunks = (B + 15) >> 4;
    for (int c = blockIdx.x; c < nchunks; c += gridDim.x) {
        const int rb = c * 16;
        int rowA = rb + l15;
        if (rowA >= B) rowA = B - 1;
        const int gidA = node_ids[rowA];

        // A-fragments: A[m][k], m = l15, k = ks*32 + lg*8 + i.
        bf16x8 ax[4], ah[4];
        #pragma unroll
        for (int ks = 0; ks < 4; ++ks) {
            ax[ks] = load_frag_f32(messages + (size_t)rowA * GRU_H + ks * 32 + lg * 8);
            ah[ks] = load_frag_f32(memory   + (size_t)gidA * GRU_H + ks * 32 + lg * 8);
        }

        f32x4 acc[6];
        #pragma unroll
        for (int g = 0; g < 6; ++g) acc[g] = (f32x4){0.f, 0.f, 0.f, 0.f};

        #pragma unroll
        for (int ks = 0; ks < 4; ++ks) {
            acc[0] = __builtin_amdgcn_mfma_f32_16x16x32_bf16(ax[ks], bfrag[0][ks], acc[0], 0, 0, 0);
            acc[1] = __builtin_amdgcn_mfma_f32_16x16x32_bf16(ax[ks], bfrag[1][ks], acc[1], 0, 0, 0);
            acc[2] = __builtin_amdgcn_mfma_f32_16x16x32_bf16(ax[ks], bfrag[2][ks], acc[2], 0, 0, 0);
            acc[3] = __builtin_amdgcn_mfma_f32_16x16x32_bf16(ah[ks], bfrag[3][ks], acc[3], 0, 0, 0);
            acc[4] = __builtin_amdgcn_mfma_f32_16x16x32_bf16(ah[ks], bfrag[4][ks], acc[4], 0, 0, 0);
            acc[5] = __builtin_amdgcn_mfma_f32_16x16x32_bf16(ah[ks], bfrag[5][ks], acc[5], 0, 0, 0);
        }

        // D layout: col = l15 (already = our 'col'), row = lg*4 + r.
        #pragma unroll
        for (int r = 0; r < 4; ++r) {
            const int row = rb + lg * 4 + r;
            if (row < B) {
                const int gid = node_ids[row];
                const float h = memory[(size_t)gid * GRU_H + col];
                const float rg = sigmoidf_((acc[0][r] + bi_r) + (acc[3][r] + bh_r));
                const float zg = sigmoidf_((acc[1][r] + bi_z) + (acc[4][r] + bh_z));
                const float ng = tanhf_((acc[2][r] + bi_n) + rg * (acc[5][r] + bh_n));
                out[(size_t)gid * GRU_H + col] = (1.f - zg) * ng + zg * h;
            }
        }
    }
}

extern "C" void kernel_launch(void* const* d_in, const int* in_sizes, int n_in,
                              void* d_out, int out_size, void* d_ws, size_t ws_size,
                              hipStream_t stream) {
    const int*   node_ids = (const int*)d_in[0];
    const float* messages = (const float*)d_in[1];
    const float* memory   = (const float*)d_in[2];
    const float* W_ih     = (const float*)d_in[3];
    const float* W_hh     = (const float*)d_in[4];
    const float* b_ih     = (const float*)d_in[5];
    const float* b_hh     = (const float*)d_in[6];
    float* out = (float*)d_out;

    const int B = in_sizes[0];                  // 100000
    const int N = in_sizes[2] / GRU_H;          // 500000

    // 1) pass-through copy memory -> out (updated rows overwritten below)
    hipMemcpyAsync(out, memory, (size_t)N * GRU_H * sizeof(float),
                   hipMemcpyDeviceToDevice, stream);

    // 2) GRU update + scatter
    const int nchunks = (B + 15) >> 4;
    int grid = nchunks < 512 ? nchunks : 512;   // 2 blocks/CU, grid-stride
    gru_update_kernel<<<grid, 512, 0, stream>>>(node_ids, messages, memory,
                                                W_ih, W_hh, b_ih, b_hh, out, B);
}